// Round 5
// baseline (322.089 us; speedup 1.0000x reference)
//
#include <hip/hip_runtime.h>
#include <math.h>

// Problem constants (fixed by the reference's shapes)
#define NROWS   131072      // 32*64*64 spatial positions
#define DFEAT   64          // feature dim (C)
#define KHALF   512         // rows per embedding table
#define HW      4096        // 64*64
#define CHW     262144      // 64*4096
#define NQOUT   8388608     // 32*64*64*64 quantized elements
#define NBLK    512         // vq_main grid: 256 rows/block, 2 blocks/CU

typedef __attribute__((ext_vector_type(8))) short   bf16x8;
typedef __attribute__((ext_vector_type(4))) float   f32x4;

__device__ __forceinline__ unsigned short f2bf(float f) {
    unsigned int u = __float_as_uint(f);
    u += 0x7FFFu + ((u >> 16) & 1u);          // round-to-nearest-even
    return (unsigned short)(u >> 16);
}
__device__ __forceinline__ float bf2f(unsigned short h) {
    return __uint_as_float(((unsigned int)h) << 16);
}

// ---------------------------------------------------------------------------
// Kernel 0 (fused prep): zero ws accumulators + cnh + pack fragments.
//   - tau < 1536: zero {loss, hist} region
//   - tau < 1024: cnh[k] = 0.5*||codes[k]||^2 (fp32 exact)
//   - all 16384:  pack codes into MFMA-B-fragment order, hi/lo bf16 split
// Layout: fragbuf[tile(64)][frag(4)][lane(64)][j(8)] ushort
//   frag 0: hi, k=0..31    frag 1: hi, k=32..63
//   frag 2: lo, k=0..31    frag 3: lo, k=32..63
// lane L of frag f holds code (tile*16 + (L&15)), feats kb..kb+7,
//   kb = (f&1)*32 + (L>>4)*8    -> ready for mfma_f32_16x16x32_bf16 B operand
// NOTE: no device-scope fences anywhere in this file. The agent-scope
// __threadfence() ticket-finalize tried in rounds 1-2 emitted per-wave
// L2 writeback/invalidate (2048 of them) and doubled vq_main's time.
// Cross-kernel visibility via the dispatch boundary (one L2 writeback total).
// ---------------------------------------------------------------------------
__global__ void vq_prep(const float* __restrict__ e0, const float* __restrict__ e1,
                        const float* __restrict__ e2, const int* __restrict__ idxp,
                        float* __restrict__ wsf, float* __restrict__ cnh,
                        unsigned short* __restrict__ fragbuf) {
    int tau = blockIdx.x * 256 + threadIdx.x;   // 64 blocks * 256 = 16384
    if (tau < 1536) wsf[tau] = 0.f;             // loss @0, hist @256..

    int idx = idxp[0];
    const float* sel = (idx == 2) ? e2 : e1;

    if (tau < 1024) {
        const float* row = (tau < KHALF) ? (e0 + (size_t)tau * DFEAT)
                                         : (sel + (size_t)(tau - KHALF) * DFEAT);
        float s = 0.f;
#pragma unroll
        for (int c = 0; c < DFEAT; ++c) s = fmaf(row[c], row[c], s);
        cnh[tau] = 0.5f * s;
    }

    int tile = tau >> 8;
    int rem  = tau & 255;
    int f    = rem >> 6;
    int L    = rem & 63;
    int code = tile * 16 + (L & 15);
    int kb   = (f & 1) * 32 + (L >> 4) * 8;
    int lo_f = f >> 1;
    const float* src = (code < KHALF) ? (e0 + (size_t)code * DFEAT)
                                      : (sel + (size_t)(code - KHALF) * DFEAT);
    unsigned short* dst = fragbuf + (size_t)tau * 8;
#pragma unroll
    for (int j = 0; j < 8; ++j) {
        float v = src[kb + j];
        unsigned short hb = f2bf(v);
        dst[j] = lo_f ? f2bf(v - bf2f(hb)) : hb;
    }
}

// ---------------------------------------------------------------------------
// Kernel 1: main VQ. Block = 512 threads = 8 waves; 256 rows/block.
// CODE-SPLIT occupancy: waves 0-3 (group 0) score tiles [0, ntiles/2) for
// rows, waves 4-7 (group 1) score tiles [ntiles/2, ntiles) for the SAME
// rows. Per-block streaming work unchanged vs 4-wave version, but
// waves/SIMD doubles 2 -> 4 for latency hiding. A-fragment build is
// duplicated across the two groups (cheap; x re-reads hit L2/L3).
// Inner loop: round-0 verified schedule (ONE 8-deep MFMA chain per
// row-tile) + ping-pong B-register sets (r4 win). Both halves' argmaxes
// merge through LDS; group 0 holds smaller k, ties keep group 0 ->
// first-min semantics preserved exactly.
// ---------------------------------------------------------------------------
#define TILE_STEP(BC0, BC1, BC2, BC3, CNC, BN0, BN1, BN2, BN3, CNN, TT, TL)   \
    {                                                                          \
        const int tl_ = (TL);                                                  \
        BN0 = fb[(tl_ * 4 + 0) * 64 + L];                                      \
        BN1 = fb[(tl_ * 4 + 1) * 64 + L];                                      \
        BN2 = fb[(tl_ * 4 + 2) * 64 + L];                                      \
        BN3 = fb[(tl_ * 4 + 3) * 64 + L];                                      \
        CNN = cnh[tl_ * 16 + m];                                               \
        const int kt_ = (TT) * 16 + m;                                         \
        _Pragma("unroll")                                                      \
        for (int rt = 0; rt < 4; ++rt) {                                       \
            f32x4 acc = {0.f, 0.f, 0.f, 0.f};                                  \
            acc = __builtin_amdgcn_mfma_f32_16x16x32_bf16(ahi[rt][0], BC0, acc, 0, 0, 0); \
            acc = __builtin_amdgcn_mfma_f32_16x16x32_bf16(ahi[rt][1], BC1, acc, 0, 0, 0); \
            acc = __builtin_amdgcn_mfma_f32_16x16x32_bf16(ahi[rt][0], BC2, acc, 0, 0, 0); \
            acc = __builtin_amdgcn_mfma_f32_16x16x32_bf16(ahi[rt][1], BC3, acc, 0, 0, 0); \
            acc = __builtin_amdgcn_mfma_f32_16x16x32_bf16(alo[rt][0], BC0, acc, 0, 0, 0); \
            acc = __builtin_amdgcn_mfma_f32_16x16x32_bf16(alo[rt][1], BC1, acc, 0, 0, 0); \
            acc = __builtin_amdgcn_mfma_f32_16x16x32_bf16(alo[rt][0], BC2, acc, 0, 0, 0); \
            acc = __builtin_amdgcn_mfma_f32_16x16x32_bf16(alo[rt][1], BC3, acc, 0, 0, 0); \
            _Pragma("unroll")                                                  \
            for (int r = 0; r < 4; ++r) {                                      \
                float s = acc[r] - CNC;                                        \
                if (s > best[rt * 4 + r]) { best[rt * 4 + r] = s; bidx[rt * 4 + r] = kt_; } \
            }                                                                  \
        }                                                                      \
    }

__global__ __launch_bounds__(512, 4) void vq_main(
        const float* __restrict__ x,
        const float* __restrict__ e0, const float* __restrict__ e1,
        const float* __restrict__ e2, const int* __restrict__ idxp,
        const float* __restrict__ cnh, const unsigned short* __restrict__ fragbuf,
        float* __restrict__ out, float* __restrict__ loss_acc,
        int* __restrict__ hist) {
    __shared__ float xsq_s[256];
    __shared__ float sc_s[512];     // [group(2)][row(256)]
    __shared__ int   bk_s[512];

    const int t  = threadIdx.x;    // 0..511
    const int w  = t >> 6;         // wave 0..7
    const int wg = w >> 2;         // tile-group 0/1
    const int wv = w & 3;          // row-group within block
    const int L  = t & 63;         // lane
    const int q  = L >> 4;         // quad
    const int m  = L & 15;

    const int rowbase = blockIdx.x * 256;   // 512 blocks; never straddles an image
    const int n  = rowbase >> 12;
    const int s0 = rowbase & 4095;

    const int idx = idxp[0];
    const float* sel = (idx == 2) ? e2 : e1;
    const int ntiles = (idx == 0) ? 32 : 64;   // always even
    const int nt2 = ntiles >> 1;
    const int t0 = wg * nt2;                   // this wave-group's tile range

    // ---- A fragments: 4 row-tiles of 16 rows, hi/lo bf16 + ||x||^2 ----
    // (duplicated across the two tile-groups; x re-reads are L2/L3 hits)
    bf16x8 ahi[4][2], alo[4][2];
    const float* xb = x + (size_t)n * CHW + (s0 + wv * 64);
#pragma unroll
    for (int rt = 0; rt < 4; ++rt) {
        const float* xr = xb + rt * 16 + m;
        float xs = 0.f;
#pragma unroll
        for (int h = 0; h < 2; ++h) {
#pragma unroll
            for (int j = 0; j < 8; ++j) {
                int c = h * 32 + q * 8 + j;
                float v = xr[(size_t)c * HW];
                xs = fmaf(v, v, xs);
                unsigned short hb = f2bf(v);
                unsigned short lb = f2bf(v - bf2f(hb));
                ahi[rt][h][j] = (short)hb;
                alo[rt][h][j] = (short)lb;
            }
        }
        // full ||x_row||^2: row features live in lanes {m, m+16, m+32, m+48}
        xs += __shfl_xor(xs, 16, 64);
        xs += __shfl_xor(xs, 32, 64);
        if (wg == 0 && q == 0) xsq_s[wv * 64 + rt * 16 + m] = xs;
    }

    // ---- stream this group's code tiles; score = x.c - 0.5||c||^2 ----
    const bf16x8* fb = (const bf16x8*)fragbuf;
    float best[16];
    int   bidx[16];
#pragma unroll
    for (int i = 0; i < 16; ++i) { best[i] = -3.4e38f; bidx[i] = 0; }

    bf16x8 X0 = fb[(t0 * 4 + 0) * 64 + L];
    bf16x8 X1 = fb[(t0 * 4 + 1) * 64 + L];
    bf16x8 X2 = fb[(t0 * 4 + 2) * 64 + L];
    bf16x8 X3 = fb[(t0 * 4 + 3) * 64 + L];
    float  Xc = cnh[t0 * 16 + m];
    bf16x8 Y0, Y1, Y2, Y3;
    float  Yc;

    for (int tt = t0; tt < t0 + nt2; tt += 2) {
        TILE_STEP(X0, X1, X2, X3, Xc, Y0, Y1, Y2, Y3, Yc, tt, tt + 1);
        const int t2 = (tt + 2 < t0 + nt2) ? tt + 2 : t0 + nt2 - 1;
        TILE_STEP(Y0, Y1, Y2, Y3, Yc, X0, X1, X2, X3, Xc, tt + 1, t2);
    }

    // ---- reduce argmax across the 16 cols (lane bits 0-3) ----
#pragma unroll
    for (int i = 0; i < 16; ++i) {
        float b = best[i]; int k = bidx[i];
#pragma unroll
        for (int off = 1; off < 16; off <<= 1) {
            float ob = __shfl_xor(b, off, 64);
            int   ok = __shfl_xor(k, off, 64);
            if (ob > b || (ob == b && ok < k)) { b = ob; k = ok; }
        }
        if (m == 0) {   // D row = q*4 + r within tile rt = i>>2
            int row = wv * 64 + (i >> 2) * 16 + q * 4 + (i & 3);
            sc_s[wg * 256 + row] = b; bk_s[wg * 256 + row] = k;
        }
    }
    __syncthreads();

    // ---- merge the two tile-groups + loss/hist (threads 0..255) ----
    if (t < 256) {
        float sA = sc_s[t];       int kA = bk_s[t];
        float sB = sc_s[256 + t]; int kB = bk_s[256 + t];
        // group 0 has strictly smaller k; ties keep group 0 (first-min)
        int   k  = (sB > sA) ? kB : kA;
        float sc = (sB > sA) ? sB : sA;
        bk_s[t] = k;                         // publish merged k for the copy
        float dist = xsq_s[t] - 2.f * sc;    // ||x||^2 - 2x.c + ||c||^2
        float l = dist;
#pragma unroll
        for (int off = 32; off > 0; off >>= 1) l += __shfl_down(l, off, 64);
        if (L == 0) atomicAdd(loss_acc, l);
        atomicAdd(&hist[k], 1);
    }
    __syncthreads();

    // ---- gather-copy: 2 threads per row, 32 feats each ----
    {
        const int row  = t & 255;
        const int half = t >> 8;
        const int k = bk_s[row];
        const float* cp = ((k < KHALF) ? (e0 + (size_t)k * DFEAT)
                                       : (sel + (size_t)(k - KHALF) * DFEAT)) + half * 32;
        const float4* cp4 = (const float4*)cp;
        float* op = out + (size_t)n * CHW + (s0 + row);
#pragma unroll
        for (int c4 = 0; c4 < 8; ++c4) {
            float4 v = cp4[c4];
            int c = half * 32 + 4 * c4;
            op[(size_t)(c + 0) * HW] = v.x;
            op[(size_t)(c + 1) * HW] = v.y;
            op[(size_t)(c + 2) * HW] = v.z;
            op[(size_t)(c + 3) * HW] = v.w;
        }
    }
}

// ---------------------------------------------------------------------------
// Kernel 2: finalize — loss scalar + perplexity from histogram. One block.
// Cross-kernel visibility of hist/loss comes from the dispatch boundary.
// ---------------------------------------------------------------------------
__global__ void vq_finalize(const float* __restrict__ wsf, const int* __restrict__ hist,
                            float* __restrict__ out) {
    __shared__ double partial[16];
    const int t = threadIdx.x;          // 1024 threads, one per bin
    double p = (double)hist[t] / (double)NROWS;
    double term = p * log(p + 1e-10);   // p==0 -> exactly 0
#pragma unroll
    for (int off = 32; off > 0; off >>= 1) term += __shfl_down(term, off, 64);
    if ((t & 63) == 0) partial[t >> 6] = term;
    __syncthreads();
    if (t == 0) {
        double s = 0.0;
        for (int i = 0; i < 16; ++i) s += partial[i];
        out[NQOUT + 1] = (float)exp(-s);                       // perplexity
        out[NQOUT]     = 1.25f * (wsf[0] / (float)NQOUT);      // q_loss + 0.25*e_loss
    }
}

// ---------------------------------------------------------------------------
extern "C" void kernel_launch(void* const* d_in, const int* in_sizes, int n_in,
                              void* d_out, int out_size, void* d_ws, size_t ws_size,
                              hipStream_t stream) {
    const float* x  = (const float*)d_in[0];
    const float* e0 = (const float*)d_in[1];
    const float* e1 = (const float*)d_in[2];
    const float* e2 = (const float*)d_in[3];
    const int* idxp = (const int*)d_in[4];
    float* out = (float*)d_out;

    // ws layout (floats): [0] loss | [256..1280) hist
    //                     [2048..3072) cnh | [4096..) fragbuf: 131072 ushort
    float* wsf      = (float*)d_ws;
    float* loss_acc = wsf;
    int*   hist     = (int*)(wsf + 256);
    float* cnh      = wsf + 2048;
    unsigned short* fragbuf = (unsigned short*)(wsf + 4096);

    vq_prep<<<64, 256, 0, stream>>>(e0, e1, e2, idxp, wsf, cnh, fragbuf);
    vq_main<<<NBLK, 512, 0, stream>>>(x, e0, e1, e2, idxp, cnh, fragbuf,
                                      out, loss_acc, hist);
    vq_finalize<<<1, 1024, 0, stream>>>(wsf, hist, out);
}

// Round 6
// 172.021 us; speedup vs baseline: 1.8724x; 1.8724x over previous
//
#include <hip/hip_runtime.h>
#include <math.h>

// Problem constants (fixed by the reference's shapes)
#define NROWS   131072      // 32*64*64 spatial positions
#define DFEAT   64          // feature dim (C)
#define KHALF   512         // rows per embedding table
#define HW      4096        // 64*64
#define CHW     262144      // 64*4096
#define NQOUT   8388608     // 32*64*64*64 quantized elements
#define NBLK    1024        // vq_main grid: 128 rows/block -> 4 blocks/CU

typedef __attribute__((ext_vector_type(8))) short   bf16x8;
typedef __attribute__((ext_vector_type(4))) float   f32x4;

__device__ __forceinline__ unsigned short f2bf(float f) {
    unsigned int u = __float_as_uint(f);
    u += 0x7FFFu + ((u >> 16) & 1u);          // round-to-nearest-even
    return (unsigned short)(u >> 16);
}
__device__ __forceinline__ float bf2f(unsigned short h) {
    return __uint_as_float(((unsigned int)h) << 16);
}

// ---------------------------------------------------------------------------
// Kernel 0 (fused prep): zero ws accumulators + cnh + pack fragments.
//   - tau < 1536: zero {loss, hist} region
//   - tau < 1024: cnh[k] = 0.5*||codes[k]||^2 (fp32 exact)
//   - all 16384:  pack codes into MFMA-B-fragment order, hi/lo bf16 split
// Layout: fragbuf[tile(64)][frag(4)][lane(64)][j(8)] ushort
//   frag 0: hi, k=0..31    frag 1: hi, k=32..63
//   frag 2: lo, k=0..31    frag 3: lo, k=32..63
// lane L of frag f holds code (tile*16 + (L&15)), feats kb..kb+7,
//   kb = (f&1)*32 + (L>>4)*8    -> ready for mfma_f32_16x16x32_bf16 B operand
// NOTE: no device-scope fences anywhere in this file (r1/r2: per-wave
// agent fence = thousands of L2 writebacks, ~80us). And all waves of a
// block must stream fragbuf in the SAME order (r5: desynchronized halves
// thrashed L2 -> FETCH 18.5MB -> 604MB, HBM-bound).
// ---------------------------------------------------------------------------
__global__ void vq_prep(const float* __restrict__ e0, const float* __restrict__ e1,
                        const float* __restrict__ e2, const int* __restrict__ idxp,
                        float* __restrict__ wsf, float* __restrict__ cnh,
                        unsigned short* __restrict__ fragbuf) {
    int tau = blockIdx.x * 256 + threadIdx.x;   // 64 blocks * 256 = 16384
    if (tau < 1536) wsf[tau] = 0.f;             // loss @0, hist @256..

    int idx = idxp[0];
    const float* sel = (idx == 2) ? e2 : e1;

    if (tau < 1024) {
        const float* row = (tau < KHALF) ? (e0 + (size_t)tau * DFEAT)
                                         : (sel + (size_t)(tau - KHALF) * DFEAT);
        float s = 0.f;
#pragma unroll
        for (int c = 0; c < DFEAT; ++c) s = fmaf(row[c], row[c], s);
        cnh[tau] = 0.5f * s;
    }

    int tile = tau >> 8;
    int rem  = tau & 255;
    int f    = rem >> 6;
    int L    = rem & 63;
    int code = tile * 16 + (L & 15);
    int kb   = (f & 1) * 32 + (L >> 4) * 8;
    int lo_f = f >> 1;
    const float* src = (code < KHALF) ? (e0 + (size_t)code * DFEAT)
                                      : (sel + (size_t)(code - KHALF) * DFEAT);
    unsigned short* dst = fragbuf + (size_t)tau * 8;
#pragma unroll
    for (int j = 0; j < 8; ++j) {
        float v = src[kb + j];
        unsigned short hb = f2bf(v);
        dst[j] = lo_f ? f2bf(v - bf2f(hb)) : hb;
    }
}

// ---------------------------------------------------------------------------
// Kernel 1: main VQ. Block = 256 threads = 4 waves; 128 rows/block
// (2 MFMA row-tiles of 16 per wave) -> grid 1024 -> 4 blocks/CU ->
// 4 waves/SIMD for latency hiding. All waves stream the same tile
// sequence (lockstep-ish) so fragbuf stays L2-resident (r5 lesson).
// Inner loop: round-0/4 verified schedule — ONE 8-deep MFMA chain per
// row-tile + ping-pong B-register sets (no copies, prefetch wait off
// the critical path). ntiles is always even (32 or 64).
// ---------------------------------------------------------------------------
#define TILE_STEP(BC0, BC1, BC2, BC3, CNC, BN0, BN1, BN2, BN3, CNN, TT, TL)   \
    {                                                                          \
        const int tl_ = (TL);                                                  \
        BN0 = fb[(tl_ * 4 + 0) * 64 + L];                                      \
        BN1 = fb[(tl_ * 4 + 1) * 64 + L];                                      \
        BN2 = fb[(tl_ * 4 + 2) * 64 + L];                                      \
        BN3 = fb[(tl_ * 4 + 3) * 64 + L];                                      \
        CNN = cnh[tl_ * 16 + m];                                               \
        const int kt_ = (TT) * 16 + m;                                         \
        _Pragma("unroll")                                                      \
        for (int rt = 0; rt < 2; ++rt) {                                       \
            f32x4 acc = {0.f, 0.f, 0.f, 0.f};                                  \
            acc = __builtin_amdgcn_mfma_f32_16x16x32_bf16(ahi[rt][0], BC0, acc, 0, 0, 0); \
            acc = __builtin_amdgcn_mfma_f32_16x16x32_bf16(ahi[rt][1], BC1, acc, 0, 0, 0); \
            acc = __builtin_amdgcn_mfma_f32_16x16x32_bf16(ahi[rt][0], BC2, acc, 0, 0, 0); \
            acc = __builtin_amdgcn_mfma_f32_16x16x32_bf16(ahi[rt][1], BC3, acc, 0, 0, 0); \
            acc = __builtin_amdgcn_mfma_f32_16x16x32_bf16(alo[rt][0], BC0, acc, 0, 0, 0); \
            acc = __builtin_amdgcn_mfma_f32_16x16x32_bf16(alo[rt][1], BC1, acc, 0, 0, 0); \
            acc = __builtin_amdgcn_mfma_f32_16x16x32_bf16(alo[rt][0], BC2, acc, 0, 0, 0); \
            acc = __builtin_amdgcn_mfma_f32_16x16x32_bf16(alo[rt][1], BC3, acc, 0, 0, 0); \
            _Pragma("unroll")                                                  \
            for (int r = 0; r < 4; ++r) {                                      \
                float s = acc[r] - CNC;                                        \
                if (s > best[rt * 4 + r]) { best[rt * 4 + r] = s; bidx[rt * 4 + r] = kt_; } \
            }                                                                  \
        }                                                                      \
    }

__global__ __launch_bounds__(256, 4) void vq_main(
        const float* __restrict__ x,
        const float* __restrict__ e0, const float* __restrict__ e1,
        const float* __restrict__ e2, const int* __restrict__ idxp,
        const float* __restrict__ cnh, const unsigned short* __restrict__ fragbuf,
        float* __restrict__ out, float* __restrict__ loss_acc,
        int* __restrict__ hist) {
    __shared__ float xsq_s[128];
    __shared__ float sc_s[128];
    __shared__ int   bk_s[128];

    const int t = threadIdx.x;
    const int w = t >> 6;          // wave in block
    const int L = t & 63;          // lane
    const int q = L >> 4;          // quad
    const int m = L & 15;

    const int rowbase = blockIdx.x * 128;   // 1024 blocks; never straddles an image
    const int n  = rowbase >> 12;
    const int s0 = rowbase & 4095;

    const int idx = idxp[0];
    const float* sel = (idx == 2) ? e2 : e1;
    const int ntiles = (idx == 0) ? 32 : 64;   // always even

    // ---- A fragments: 2 row-tiles of 16 rows, hi/lo bf16 + ||x||^2 ----
    bf16x8 ahi[2][2], alo[2][2];
    const float* xb = x + (size_t)n * CHW + (s0 + w * 32);
#pragma unroll
    for (int rt = 0; rt < 2; ++rt) {
        const float* xr = xb + rt * 16 + m;
        float xs = 0.f;
#pragma unroll
        for (int h = 0; h < 2; ++h) {
#pragma unroll
            for (int j = 0; j < 8; ++j) {
                int c = h * 32 + q * 8 + j;
                float v = xr[(size_t)c * HW];
                xs = fmaf(v, v, xs);
                unsigned short hb = f2bf(v);
                unsigned short lb = f2bf(v - bf2f(hb));
                ahi[rt][h][j] = (short)hb;
                alo[rt][h][j] = (short)lb;
            }
        }
        // full ||x_row||^2: row features live in lanes {m, m+16, m+32, m+48}
        xs += __shfl_xor(xs, 16, 64);
        xs += __shfl_xor(xs, 32, 64);
        if (q == 0) xsq_s[w * 32 + rt * 16 + m] = xs;
    }

    // ---- stream the code tiles; score = x.c - 0.5||c||^2, argMAX ----
    const bf16x8* fb = (const bf16x8*)fragbuf;
    float best[8];
    int   bidx[8];
#pragma unroll
    for (int i = 0; i < 8; ++i) { best[i] = -3.4e38f; bidx[i] = 0; }

    bf16x8 X0 = fb[0 * 64 + L];
    bf16x8 X1 = fb[1 * 64 + L];
    bf16x8 X2 = fb[2 * 64 + L];
    bf16x8 X3 = fb[3 * 64 + L];
    float  Xc = cnh[m];
    bf16x8 Y0, Y1, Y2, Y3;
    float  Yc;

    for (int tt = 0; tt < ntiles; tt += 2) {
        TILE_STEP(X0, X1, X2, X3, Xc, Y0, Y1, Y2, Y3, Yc, tt, tt + 1);
        const int t2 = (tt + 2 < ntiles) ? tt + 2 : ntiles - 1;
        TILE_STEP(Y0, Y1, Y2, Y3, Yc, X0, X1, X2, X3, Xc, tt + 1, t2);
    }

    // ---- reduce argmax across the 16 cols (lane bits 0-3) ----
#pragma unroll
    for (int i = 0; i < 8; ++i) {
        float b = best[i]; int k = bidx[i];
#pragma unroll
        for (int off = 1; off < 16; off <<= 1) {
            float ob = __shfl_xor(b, off, 64);
            int   ok = __shfl_xor(k, off, 64);
            if (ob > b || (ob == b && ok < k)) { b = ob; k = ok; }
        }
        if (m == 0) {   // D row = q*4 + r within tile rt = i>>2
            int row = w * 32 + (i >> 2) * 16 + q * 4 + (i & 3);
            sc_s[row] = b; bk_s[row] = k;
        }
    }
    __syncthreads();

    // ---- epilogue part 1: loss + histogram, one thread per row (t < 128) ----
    if (t < 128) {
        const int k = bk_s[t];
        float dist = xsq_s[t] - 2.f * sc_s[t];   // ||x||^2 - 2x.c + ||c||^2
        float l = dist;
#pragma unroll
        for (int off = 32; off > 0; off >>= 1) l += __shfl_down(l, off, 64);
        if (L == 0) atomicAdd(loss_acc, l);
        atomicAdd(&hist[k], 1);
    }

    // ---- epilogue part 2: gather-copy, 2 threads per row (32 feats each) ----
    {
        const int row  = t & 127;
        const int half = t >> 7;
        const int k = bk_s[row];
        const float* cp = ((k < KHALF) ? (e0 + (size_t)k * DFEAT)
                                       : (sel + (size_t)(k - KHALF) * DFEAT)) + half * 32;
        const float4* cp4 = (const float4*)cp;
        float* op = out + (size_t)n * CHW + (s0 + row);
#pragma unroll
        for (int c4 = 0; c4 < 8; ++c4) {
            float4 v = cp4[c4];
            int c = half * 32 + 4 * c4;
            op[(size_t)(c + 0) * HW] = v.x;
            op[(size_t)(c + 1) * HW] = v.y;
            op[(size_t)(c + 2) * HW] = v.z;
            op[(size_t)(c + 3) * HW] = v.w;
        }
    }
}

// ---------------------------------------------------------------------------
// Kernel 2: finalize — loss scalar + perplexity from histogram. One block.
// Cross-kernel visibility of hist/loss comes from the dispatch boundary.
// ---------------------------------------------------------------------------
__global__ void vq_finalize(const float* __restrict__ wsf, const int* __restrict__ hist,
                            float* __restrict__ out) {
    __shared__ double partial[16];
    const int t = threadIdx.x;          // 1024 threads, one per bin
    double p = (double)hist[t] / (double)NROWS;
    double term = p * log(p + 1e-10);   // p==0 -> exactly 0
#pragma unroll
    for (int off = 32; off > 0; off >>= 1) term += __shfl_down(term, off, 64);
    if ((t & 63) == 0) partial[t >> 6] = term;
    __syncthreads();
    if (t == 0) {
        double s = 0.0;
        for (int i = 0; i < 16; ++i) s += partial[i];
        out[NQOUT + 1] = (float)exp(-s);                       // perplexity
        out[NQOUT]     = 1.25f * (wsf[0] / (float)NQOUT);      // q_loss + 0.25*e_loss
    }
}

// ---------------------------------------------------------------------------
extern "C" void kernel_launch(void* const* d_in, const int* in_sizes, int n_in,
                              void* d_out, int out_size, void* d_ws, size_t ws_size,
                              hipStream_t stream) {
    const float* x  = (const float*)d_in[0];
    const float* e0 = (const float*)d_in[1];
    const float* e1 = (const float*)d_in[2];
    const float* e2 = (const float*)d_in[3];
    const int* idxp = (const int*)d_in[4];
    float* out = (float*)d_out;

    // ws layout (floats): [0] loss | [256..1280) hist
    //                     [2048..3072) cnh | [4096..) fragbuf: 131072 ushort
    float* wsf      = (float*)d_ws;
    float* loss_acc = wsf;
    int*   hist     = (int*)(wsf + 256);
    float* cnh      = wsf + 2048;
    unsigned short* fragbuf = (unsigned short*)(wsf + 4096);

    vq_prep<<<64, 256, 0, stream>>>(e0, e1, e2, idxp, wsf, cnh, fragbuf);
    vq_main<<<NBLK, 256, 0, stream>>>(x, e0, e1, e2, idxp, cnh, fragbuf,
                                      out, loss_acc, hist);
    vq_finalize<<<1, 1024, 0, stream>>>(wsf, hist, out);
}